// Round 11
// baseline (381.937 us; speedup 1.0000x reference)
//
#include <hip/hip_runtime.h>
#include <hip/hip_bf16.h>
#include <math.h>

#define NNODES 50000
#define NEDGES 800000
#define NGRAPHS 128
#define SCAN_B ((NNODES + 255) / 256)   // 196 scan blocks

typedef __attribute__((ext_vector_type(8))) short bf16x8;   // 8 bf16 = 4 VGPR
typedef __attribute__((ext_vector_type(4))) float f32x4;    // MFMA acc

__device__ __forceinline__ unsigned short f2bf(float f) {   // fp32->bf16 RNE
    unsigned int u = __float_as_uint(f);
    return (unsigned short)((u + 0x7FFFu + ((u >> 16) & 1u)) >> 16);
}
__device__ __forceinline__ unsigned pack2bf(float a, float b) {
    return (unsigned)f2bf(a) | ((unsigned)f2bf(b) << 16);
}
__device__ __forceinline__ float2 bf2f2(unsigned int u) {   // bf16x2 -> 2x fp32
    float2 f;
    f.x = __uint_as_float(u << 16);
    f.y = __uint_as_float(u & 0xFFFF0000u);
    return f;
}

// ---------------------------------------------------------------- CSR build
__global__ void count_edges(const int* __restrict__ ei, int* __restrict__ cnt) {
    int e = blockIdx.x * 256 + threadIdx.x;
    if (e < NEDGES) atomicAdd(&cnt[ei[NEDGES + e]], 1);
}

// 3-pass device-wide exclusive scan
__global__ __launch_bounds__(256)
void scan_pass1(const int* __restrict__ cnt, int* __restrict__ bsum) {
    const int t = threadIdx.x;
    const int i = blockIdx.x * 256 + t;
    int v = (i < NNODES) ? cnt[i] : 0;
#pragma unroll
    for (int off = 32; off > 0; off >>= 1) v += __shfl_xor(v, off, 64);
    __shared__ int ws[4];
    if ((t & 63) == 0) ws[t >> 6] = v;
    __syncthreads();
    if (t == 0) bsum[blockIdx.x] = ws[0] + ws[1] + ws[2] + ws[3];
}

__global__ __launch_bounds__(256)
void scan_pass2(const int* __restrict__ bsum, int* __restrict__ boff) {
    const int t = threadIdx.x;
    const int v = (t < SCAN_B) ? bsum[t] : 0;
    __shared__ int a[256];
    a[t] = v;
    __syncthreads();
    for (int off = 1; off < 256; off <<= 1) {
        const int u = (t >= off) ? a[t - off] : 0;
        __syncthreads();
        a[t] += u;
        __syncthreads();
    }
    if (t < SCAN_B) boff[t] = a[t] - v;   // exclusive
}

__global__ __launch_bounds__(256)
void scan_pass3(const int* __restrict__ cnt, const int* __restrict__ boff,
                int* __restrict__ rowptr, int* __restrict__ wpos) {
    const int t = threadIdx.x;
    const int i = blockIdx.x * 256 + t;
    const int v = (i < NNODES) ? cnt[i] : 0;
    __shared__ int a[256];
    a[t] = v;
    __syncthreads();
    for (int off = 1; off < 256; off <<= 1) {
        const int u = (t >= off) ? a[t - off] : 0;
        __syncthreads();
        a[t] += u;
        __syncthreads();
    }
    if (i < NNODES) {
        const int e = boff[blockIdx.x] + a[t] - v;
        rowptr[i] = e;
        wpos[i]   = e;
    }
    if (i == 0) rowptr[NNODES] = NEDGES;
}

__global__ void fill_csr(const int* __restrict__ ei, int* __restrict__ wpos,
                         int* __restrict__ colsrc) {
    int e = blockIdx.x * 256 + threadIdx.x;
    if (e < NEDGES) {
        int d = ei[NEDGES + e];
        int slot = atomicAdd(&wpos[d], 1);
        colsrc[slot] = ei[e];            // store src node id
    }
}

// --------- merged weight prep: Wt transpose+bf16 (512 blks) + wl@wl2 (33 blks)
__global__ __launch_bounds__(256)
void prep_all(const float* __restrict__ wq1, const float* __restrict__ wk1,
              const float* __restrict__ wv1, const float* __restrict__ ws1,
              const float* __restrict__ wq2, const float* __restrict__ wk2,
              const float* __restrict__ wv2, const float* __restrict__ ws2,
              const float* __restrict__ wl, const float* __restrict__ bl,
              const float* __restrict__ wl2, const float* __restrict__ bl2,
              unsigned short* __restrict__ Wt, float* __restrict__ wf,
              float* __restrict__ bf) {
    const int b = blockIdx.x;
    if (b < 512) {                       // Wt: layer/sel/sub-block from b
        const int layer = b >> 8;
        const int sel   = (b >> 6) & 3;
        const float* W = layer == 0
            ? (sel == 0 ? wq1 : sel == 1 ? wk1 : sel == 2 ? wv1 : ws1)
            : (sel == 0 ? wq2 : sel == 1 ? wk2 : sel == 2 ? wv2 : ws2);
        const int idx = (b & 63) * 256 + threadIdx.x;   // 0..16383
        const int col = idx & 127;
        const int k   = idx >> 7;
        Wt[layer * 65536 + sel * 16384 + col * 128 + k] = f2bf(W[k * 128 + col]);
    } else {                             // fused head weight: 4 rows per block
        const int g = (b - 512) * 4 + (threadIdx.x >> 6);
        const int l = threadIdx.x & 63;
        if (g <= 128) {
            const float* row = (g < 128) ? &wl[g * 128] : bl;
            float s = row[l] * wl2[l] + row[64 + l] * wl2[64 + l];
#pragma unroll
            for (int off = 32; off > 0; off >>= 1) s += __shfl_xor(s, off, 64);
            if (l == 0) {
                if (g < 128) wf[g] = s;
                else         bf[0] = s + bl2[0];
            }
        }
    }
}

// ------------------------------------------------------------ MFMA fused GEMM
// O[sel] = F @ W[sel] + b[sel] via mfma_f32_16x16x32_bf16 (fp32 accum).
// OPERAND-SWAPPED: D = mfma(Wfrag, NodeFrag) so D.col = node, D.row = 4
// consecutive weight cols -> bias init is a float4 load, epilogue is one
// 8-byte packed store per acc (was 4 scalar ushort stores). LDS layout and
// fragment reads are unchanged (A/B frag index maps are symmetric).
template <bool A_BF16>
__global__ __launch_bounds__(256)
void gemm_qkvs(const void* __restrict__ Fv, const unsigned short* __restrict__ Wt,
               const float* __restrict__ bq, const float* __restrict__ bk,
               const float* __restrict__ bv, const float* __restrict__ bsk,
               unsigned short* __restrict__ Qb, unsigned short* __restrict__ Kb,
               unsigned short* __restrict__ Vb, unsigned short* __restrict__ Hb) {
    __shared__ __align__(16) unsigned short As[128][136];      // 34.8 KB
    __shared__ __align__(16) unsigned short Bt[2][64][136];    // 2 x 17.4 KB
    const int t    = threadIdx.x;
    const int m0   = blockIdx.x * 128;
    const int lane = t & 63;
    const int w    = t >> 6;            // wave 0..3 -> rows [w*32, w*32+32)
    const int l15  = lane & 15;
    const int lg   = lane >> 4;         // 0..3

    {   // stage A: 128 rows x 128 k
        const int row = t >> 1;
        const int kh  = (t & 1) * 64;
        const int gr  = min(m0 + row, NNODES - 1);   // tail clamp; stores guarded
        if constexpr (A_BF16) {
            const unsigned short* src = &((const unsigned short*)Fv)[(size_t)gr * 128 + kh];
#pragma unroll
            for (int p = 0; p < 8; ++p)
                *(uint4*)&As[row][kh + p * 8] = *(const uint4*)&src[p * 8];
        } else {
            const float* src = &((const float*)Fv)[(size_t)gr * 128 + kh];
#pragma unroll
            for (int p = 0; p < 16; ++p) {
                const float4 v = *(const float4*)&src[p * 4];
                ushort4 u;
                u.x = f2bf(v.x); u.y = f2bf(v.y); u.z = f2bf(v.z); u.w = f2bf(v.w);
                *(ushort4*)&As[row][kh + p * 4] = u;
            }
        }
    }

#define STAGE_B(BUF, SL)                                                       \
    {                                                                          \
        const int sel_ = (SL) >> 1, c0_ = ((SL) & 1) * 64;                     \
        const int col = t >> 2, kb = (t & 3) * 32;                             \
        const unsigned short* src = &Wt[sel_ * 16384 + (c0_ + col) * 128 + kb];\
        _Pragma("unroll")                                                      \
        for (int p = 0; p < 4; ++p)                                            \
            *(uint4*)&Bt[BUF][col][kb + p * 8] = *(const uint4*)&src[p * 8];   \
    }

    STAGE_B(0, 0)
    __syncthreads();                     // As + Bt[0] ready

    for (int sl = 0; sl < 8; ++sl) {
        const int cur = sl & 1;
        if (sl < 7) STAGE_B(cur ^ 1, sl + 1)   // loads in flight during MFMA

        const int sel = sl >> 1;
        const int c0  = (sl & 1) * 64;
        const float* bias = sel == 0 ? bq : sel == 1 ? bk : sel == 2 ? bv : bsk;
        unsigned short* Ob = sel == 0 ? Qb : sel == 1 ? Kb : sel == 2 ? Vb : Hb;

        const int cb = c0 + lg * 4;      // this lane-group's weight-col base
        const float4 bv0 = *(const float4*)&bias[cb];
        const float4 bv1 = *(const float4*)&bias[cb + 16];
        const float4 bv2 = *(const float4*)&bias[cb + 32];
        const float4 bv3 = *(const float4*)&bias[cb + 48];
        f32x4 a00 = {bv0.x, bv0.y, bv0.z, bv0.w};    // node-tile 0, col-tile 0..3
        f32x4 a01 = {bv1.x, bv1.y, bv1.z, bv1.w};
        f32x4 a02 = {bv2.x, bv2.y, bv2.z, bv2.w};
        f32x4 a03 = {bv3.x, bv3.y, bv3.z, bv3.w};
        f32x4 a10 = a00, a11 = a01, a12 = a02, a13 = a03;   // node-tile 1
#pragma unroll
        for (int ks = 0; ks < 4; ++ks) {
            const int kof = ks * 32 + lg * 8;
            const bf16x8 nf0 = *(const bf16x8*)&As[w * 32 + l15][kof];
            const bf16x8 nf1 = *(const bf16x8*)&As[w * 32 + 16 + l15][kof];
            const bf16x8 wf0 = *(const bf16x8*)&Bt[cur][l15][kof];
            const bf16x8 wf1 = *(const bf16x8*)&Bt[cur][16 + l15][kof];
            const bf16x8 wf2 = *(const bf16x8*)&Bt[cur][32 + l15][kof];
            const bf16x8 wf3 = *(const bf16x8*)&Bt[cur][48 + l15][kof];
            a00 = __builtin_amdgcn_mfma_f32_16x16x32_bf16(wf0, nf0, a00, 0, 0, 0);
            a01 = __builtin_amdgcn_mfma_f32_16x16x32_bf16(wf1, nf0, a01, 0, 0, 0);
            a02 = __builtin_amdgcn_mfma_f32_16x16x32_bf16(wf2, nf0, a02, 0, 0, 0);
            a03 = __builtin_amdgcn_mfma_f32_16x16x32_bf16(wf3, nf0, a03, 0, 0, 0);
            a10 = __builtin_amdgcn_mfma_f32_16x16x32_bf16(wf0, nf1, a10, 0, 0, 0);
            a11 = __builtin_amdgcn_mfma_f32_16x16x32_bf16(wf1, nf1, a11, 0, 0, 0);
            a12 = __builtin_amdgcn_mfma_f32_16x16x32_bf16(wf2, nf1, a12, 0, 0, 0);
            a13 = __builtin_amdgcn_mfma_f32_16x16x32_bf16(wf3, nf1, a13, 0, 0, 0);
        }

        const int gn0 = m0 + w * 32 + l15;       // node for node-tile 0
        const int gn1 = gn0 + 16;                // node for node-tile 1
#define STP(ACC, CT, GN)                                                       \
        if ((GN) < NNODES) {                                                   \
            uint2 o;                                                           \
            o.x = pack2bf(ACC[0], ACC[1]);                                     \
            o.y = pack2bf(ACC[2], ACC[3]);                                     \
            *(uint2*)&Ob[(size_t)(GN) * 128 + cb + (CT) * 16] = o;             \
        }
        STP(a00, 0, gn0) STP(a01, 1, gn0) STP(a02, 2, gn0) STP(a03, 3, gn0)
        STP(a10, 0, gn1) STP(a11, 1, gn1) STP(a12, 2, gn1) STP(a13, 3, gn1)
#undef STP
        __syncthreads();                 // one barrier per slice
    }
#undef STAGE_B
}

// --------------------------------------------- per-dst-node online softmax agg
// One WAVE per node; 4 edge slots x 16 lanes; lane owns a channel OCTET
// (c = (l&15)*8, head = (l&15)>>2). Defer-max (T13): m rescale only when
// !__all(p <= m+8), exp2-domain scores (log2e/sqrt(32) folded into Q).
// All node tensors bf16. FUSE_HEAD=false: H <- relu(skip+msg) (bf16).
// FUSE_HEAD=true: r[n] = dot(relu(skip+msg), wf).
template <bool FUSE_HEAD>
__global__ __launch_bounds__(128)
void attn_agg(const unsigned short* __restrict__ Qb,
              const unsigned short* __restrict__ Kb,
              const unsigned short* __restrict__ Vb,
              unsigned short* __restrict__ Hb,
              const int* __restrict__ rowptr, const int* __restrict__ colsrc,
              const float* __restrict__ wf, float* __restrict__ r) {
    const int n = blockIdx.x * 2 + (threadIdx.x >> 6);
    const int l = threadIdx.x & 63;
    const int e = l >> 4;                    // edge slot 0..3
    const int c = (l & 15) * 8;              // channel octet base
    const uint4 qu = *(const uint4*)&Qb[(size_t)n * 128 + c];
    const float S = 0.17677669529663687f * 1.4426950408889634f; // log2e/sqrt(32)
    const float2 t01 = bf2f2(qu.x), t23 = bf2f2(qu.y);
    const float2 t45 = bf2f2(qu.z), t67 = bf2f2(qu.w);
    const float q0 = t01.x * S, q1 = t01.y * S, q2 = t23.x * S, q3 = t23.y * S;
    const float q4 = t45.x * S, q5 = t45.y * S, q6 = t67.x * S, q7 = t67.y * S;
    const int beg = rowptr[n], end = rowptr[n + 1];
    const int cnt = end - beg;

    float m = -INFINITY, s = 0.f;
    float a0 = 0.f, a1 = 0.f, a2 = 0.f, a3 = 0.f;
    float a4 = 0.f, a5 = 0.f, a6 = 0.f, a7 = 0.f;

    uint4 ku, vu;                            // prefetch (this slot's edge)
    if (cnt > 0) {
        const int src = colsrc[min(beg + e, end - 1)];
        ku = *(const uint4*)&Kb[(size_t)src * 128 + c];
        vu = *(const uint4*)&Vb[(size_t)src * 128 + c];
    }
    for (int i = beg; i < end; i += 4) {
        const uint4 kc = ku, vc = vu;
        const bool valid = (i + e) < end;
        if (i + 4 < end) {                   // prefetch next 4 edges
            const int srcN = colsrc[min(i + 4 + e, end - 1)];
            ku = *(const uint4*)&Kb[(size_t)srcN * 128 + c];
            vu = *(const uint4*)&Vb[(size_t)srcN * 128 + c];
        }
        const float2 k01 = bf2f2(kc.x), k23 = bf2f2(kc.y);
        const float2 k45 = bf2f2(kc.z), k67 = bf2f2(kc.w);
        float p = q0 * k01.x;
        p = fmaf(q1, k01.y, p); p = fmaf(q2, k23.x, p); p = fmaf(q3, k23.y, p);
        p = fmaf(q4, k45.x, p); p = fmaf(q5, k45.y, p); p = fmaf(q6, k67.x, p);
        p = fmaf(q7, k67.y, p);
        p += __shfl_xor(p, 2);
        p += __shfl_xor(p, 1);               // per-head edge score (4-lane group)
        if (!valid) p = -INFINITY;
        if (!__all(p <= m + 8.f)) {          // rare rescale (always on iter 0)
            float pm = fmaxf(p, __shfl_xor(p, 16));
            pm = fmaxf(pm, __shfl_xor(pm, 32));      // max over 4 edge slots
            const float nm = fmaxf(m, pm);
            const float sc = exp2f(m - nm);          // 0 on first iteration
            s *= sc;
            a0 *= sc; a1 *= sc; a2 *= sc; a3 *= sc;
            a4 *= sc; a5 *= sc; a6 *= sc; a7 *= sc;
            m = nm;
        }
        const float w = exp2f(p - m);        // 0 for invalid edge
        s += w;
        const float2 v01 = bf2f2(vc.x), v23 = bf2f2(vc.y);
        const float2 v45 = bf2f2(vc.z), v67 = bf2f2(vc.w);
        a0 = fmaf(w, v01.x, a0); a1 = fmaf(w, v01.y, a1);
        a2 = fmaf(w, v23.x, a2); a3 = fmaf(w, v23.y, a3);
        a4 = fmaf(w, v45.x, a4); a5 = fmaf(w, v45.y, a5);
        a6 = fmaf(w, v67.x, a6); a7 = fmaf(w, v67.y, a7);
    }
    // combine the 4 edge slots (identical m)
    s  += __shfl_xor(s, 16);  s  += __shfl_xor(s, 32);
    a0 += __shfl_xor(a0, 16); a0 += __shfl_xor(a0, 32);
    a1 += __shfl_xor(a1, 16); a1 += __shfl_xor(a1, 32);
    a2 += __shfl_xor(a2, 16); a2 += __shfl_xor(a2, 32);
    a3 += __shfl_xor(a3, 16); a3 += __shfl_xor(a3, 32);
    a4 += __shfl_xor(a4, 16); a4 += __shfl_xor(a4, 32);
    a5 += __shfl_xor(a5, 16); a5 += __shfl_xor(a5, 32);
    a6 += __shfl_xor(a6, 16); a6 += __shfl_xor(a6, 32);
    a7 += __shfl_xor(a7, 16); a7 += __shfl_xor(a7, 32);

    const uint4 hu = *(const uint4*)&Hb[(size_t)n * 128 + c];
    const float2 h01 = bf2f2(hu.x), h23 = bf2f2(hu.y);
    const float2 h45 = bf2f2(hu.z), h67 = bf2f2(hu.w);
    float o0 = h01.x, o1 = h01.y, o2 = h23.x, o3 = h23.y;
    float o4 = h45.x, o5 = h45.y, o6 = h67.x, o7 = h67.y;
    if (cnt > 0) {
        const float inv = 1.f / s;
        o0 = fmaf(a0, inv, o0); o1 = fmaf(a1, inv, o1);
        o2 = fmaf(a2, inv, o2); o3 = fmaf(a3, inv, o3);
        o4 = fmaf(a4, inv, o4); o5 = fmaf(a5, inv, o5);
        o6 = fmaf(a6, inv, o6); o7 = fmaf(a7, inv, o7);
    }
    o0 = fmaxf(o0, 0.f); o1 = fmaxf(o1, 0.f); o2 = fmaxf(o2, 0.f);
    o3 = fmaxf(o3, 0.f); o4 = fmaxf(o4, 0.f); o5 = fmaxf(o5, 0.f);
    o6 = fmaxf(o6, 0.f); o7 = fmaxf(o7, 0.f);
    if (!FUSE_HEAD) {
        if (e == 0) {                        // one slot writes the octet
            uint4 o;
            o.x = pack2bf(o0, o1); o.y = pack2bf(o2, o3);
            o.z = pack2bf(o4, o5); o.w = pack2bf(o6, o7);
            *(uint4*)&Hb[(size_t)n * 128 + c] = o;
        }
    } else {
        const float4 wA = *(const float4*)&wf[c];
        const float4 wB = *(const float4*)&wf[c + 4];
        float val = fmaf(o0, wA.x, fmaf(o1, wA.y, fmaf(o2, wA.z, o3 * wA.w)));
        val = fmaf(o4, wB.x, fmaf(o5, wB.y, fmaf(o6, wB.z, fmaf(o7, wB.w, val))));
        val += __shfl_xor(val, 8);
        val += __shfl_xor(val, 4);
        val += __shfl_xor(val, 2);
        val += __shfl_xor(val, 1);           // sum over the 16-lane octet group
        if (l == 0) r[n] = val;
    }
}

// ----------------------------------------------- per-graph mean (batch sorted)
__global__ __launch_bounds__(256)
void graph_pool(const float* __restrict__ r, const int* __restrict__ batch,
                const float* __restrict__ bf, float* __restrict__ out) {
    const int g = blockIdx.x;
    const int t = threadIdx.x;
    int lo = 0, hi = NNODES;
    while (lo < hi) { int mid = (lo + hi) >> 1; if (batch[mid] < g) lo = mid + 1; else hi = mid; }
    const int beg = lo;
    lo = beg; hi = NNODES;
    while (lo < hi) { int mid = (lo + hi) >> 1; if (batch[mid] < g + 1) lo = mid + 1; else hi = mid; }
    const int end = lo;

    float s = 0.f;
    for (int i = beg + t; i < end; i += 256) s += r[i];
#pragma unroll
    for (int off = 32; off > 0; off >>= 1) s += __shfl_xor(s, off, 64);
    __shared__ float pw[4];
    if ((t & 63) == 0) pw[t >> 6] = s;
    __syncthreads();
    if (t == 0) {
        const float cnt = (float)(end - beg);
        const float tot = pw[0] + pw[1] + pw[2] + pw[3] + cnt * bf[0];
        out[g] = tot / fmaxf(cnt, 1.f);
    }
}

// ---------------------------------------------------------------------- launch
extern "C" void kernel_launch(void* const* d_in, const int* in_sizes, int n_in,
                              void* d_out, int out_size, void* d_ws, size_t ws_size,
                              hipStream_t stream) {
    const float* x     = (const float*)d_in[0];
    const int*   ei    = (const int*)d_in[1];
    const int*   batch = (const int*)d_in[2];
    const float* wq1 = (const float*)d_in[3];  const float* bq1 = (const float*)d_in[4];
    const float* wk1 = (const float*)d_in[5];  const float* bk1 = (const float*)d_in[6];
    const float* wv1 = (const float*)d_in[7];  const float* bv1 = (const float*)d_in[8];
    const float* ws1 = (const float*)d_in[9];  const float* bs1 = (const float*)d_in[10];
    const float* wq2 = (const float*)d_in[11]; const float* bq2 = (const float*)d_in[12];
    const float* wk2 = (const float*)d_in[13]; const float* bk2 = (const float*)d_in[14];
    const float* wv2 = (const float*)d_in[15]; const float* bv2 = (const float*)d_in[16];
    const float* ws2 = (const float*)d_in[17]; const float* bs2 = (const float*)d_in[18];
    const float* wl  = (const float*)d_in[19]; const float* bl  = (const float*)d_in[20];
    const float* wl2 = (const float*)d_in[21]; const float* bl2 = (const float*)d_in[22];

    char* wsb = (char*)d_ws;
    size_t off = 0;
    auto carve = [&](size_t bytes) -> void* {
        void* p = wsb + off;
        off = (off + bytes + 255) & ~(size_t)255;
        return p;
    };
    const size_t NB = (size_t)NNODES * 128 * 2;   // bf16 node matrix: 12.8 MB
    unsigned short* Qb = (unsigned short*)carve(NB);
    unsigned short* Kb = (unsigned short*)carve(NB);
    unsigned short* Vb = (unsigned short*)carve(NB);
    unsigned short* H1 = (unsigned short*)carve(NB);
    unsigned short* H2 = (unsigned short*)carve(NB);
    int*   rowptr = (int*)carve((NNODES + 1) * sizeof(int));
    int*   wpos   = (int*)carve(NNODES * sizeof(int));
    int*   cnt    = (int*)carve(NNODES * sizeof(int));
    int*   colsrc = (int*)carve(NEDGES * sizeof(int));
    int*   bsum   = (int*)carve(256 * sizeof(int));
    int*   boff   = (int*)carve(256 * sizeof(int));
    float* wf     = (float*)carve(129 * sizeof(float));
    float* bf     = wf + 128;
    float* nodeval = (float*)carve(NNODES * sizeof(float));
    unsigned short* Wt = (unsigned short*)carve(131072 * sizeof(unsigned short));

    hipMemsetAsync(cnt, 0, NNODES * sizeof(int), stream);

    count_edges<<<(NEDGES + 255) / 256, 256, 0, stream>>>(ei, cnt);
    scan_pass1<<<SCAN_B, 256, 0, stream>>>(cnt, bsum);
    scan_pass2<<<1, 256, 0, stream>>>(bsum, boff);
    scan_pass3<<<SCAN_B, 256, 0, stream>>>(cnt, boff, rowptr, wpos);
    fill_csr<<<(NEDGES + 255) / 256, 256, 0, stream>>>(ei, wpos, colsrc);
    prep_all<<<545, 256, 0, stream>>>(wq1, wk1, wv1, ws1, wq2, wk2, wv2, ws2,
                                      wl, bl, wl2, bl2, Wt, wf, bf);

    const int ggrid = (NNODES + 127) / 128;    // 391 blocks
    const int agrid = NNODES / 2;              // 2 nodes (waves) per block
    // layer 1
    gemm_qkvs<false><<<ggrid, 256, 0, stream>>>(x, Wt, bq1, bk1, bv1, bs1,
                                                Qb, Kb, Vb, H1);
    attn_agg<false><<<agrid, 128, 0, stream>>>(Qb, Kb, Vb, H1, rowptr, colsrc,
                                               nullptr, nullptr);
    // layer 2
    gemm_qkvs<true><<<ggrid, 256, 0, stream>>>(H1, Wt + 65536, bq2, bk2, bv2, bs2,
                                               Qb, Kb, Vb, H2);
    attn_agg<true><<<agrid, 128, 0, stream>>>(Qb, Kb, Vb, H2, rowptr, colsrc,
                                              wf, nodeval);
    // per-graph mean over sorted batch ranges (no atomics)
    graph_pool<<<NGRAPHS, 256, 0, stream>>>(nodeval, batch, bf, (float*)d_out);
}